// Round 1
// baseline (13.406 us; speedup 1.0000x reference)
//
#include <hip/hip_runtime.h>

// Problem constants (from setup_inputs): B=4, N=64 labels, H=W=512.
#define BB 4
#define NN 64
#define HH 512
#define WW 512

#define LOG2E 1.4426950408889634f

// Kernel 1: per (b,n) compute 1/(sum_x gx * sum_y gy) into ws.
// 256 blocks x 64 threads (one wave). Each lane covers 8 x's and 8 y's.
__global__ __launch_bounds__(64) void norm_kernel(
    const float* __restrict__ labels,   // (B,N,2)
    const float* __restrict__ sigma,    // scalar
    float* __restrict__ invn)           // (B*N)
{
    const int bn = blockIdx.x;          // 0..B*N-1
    const int t  = threadIdx.x;         // 0..63
    const float lx = labels[bn * 2 + 0];
    const float ly = labels[bn * 2 + 1];
    const float s  = sigma[0];
    const float c2 = -LOG2E / (2.0f * s * s);   // exp(-d2/(2s^2)) = exp2(c2*d2)

    float sx = 0.0f, sy = 0.0f;
#pragma unroll
    for (int k = 0; k < WW; k += 64) {
        const float v  = (float)(t + k);
        const float dx = v - lx;
        const float dy = v - ly;
        sx += __builtin_amdgcn_exp2f(c2 * dx * dx);
        sy += __builtin_amdgcn_exp2f(c2 * dy * dy);
    }
    // 64-lane butterfly reduce
#pragma unroll
    for (int off = 32; off > 0; off >>= 1) {
        sx += __shfl_xor(sx, off, 64);
        sy += __shfl_xor(sy, off, 64);
    }
    if (t == 0) invn[bn] = 1.0f / (sx * sy);
}

// Kernel 2: one block per (b, y-row), 512 threads = one pixel per thread.
// Wave 0 compacts the labels whose gaussian reaches this row; all threads
// then loop over the (few) survivors.
__global__ __launch_bounds__(512) void density_kernel(
    const float* __restrict__ labels,   // (B,N,2)
    const float* __restrict__ sigma,
    const float* __restrict__ invn,     // (B*N)
    float* __restrict__ out)            // (B,1,H,W)
{
    const int b = blockIdx.x >> 9;            // blockIdx.x / HH
    const int y = blockIdx.x & (HH - 1);
    const int t = threadIdx.x;                // 0..511 = x

    __shared__ float lx_s[NN];
    __shared__ float dy2_s[NN];
    __shared__ float w_s[NN];
    __shared__ int   cnt_s;

    const float s  = sigma[0];
    const float c2 = -LOG2E / (2.0f * s * s);

    if (t < NN) {                             // first wave only (NN==64)
        const float lx  = labels[(b * NN + t) * 2 + 0];
        const float ly  = labels[(b * NN + t) * 2 + 1];
        const float dy  = (float)y - ly;
        const float dy2 = dy * dy;
        // Keep iff max possible contribution exp2(c2*dy2) >= 2^-18.
        // Dropped terms contribute < 2^-18 * invn (~4e-8) each; 64 of them
        // is still ~2.4e-6, far under the 5.9e-4 threshold.
        const bool keep = (c2 * dy2 > -18.0f);
        const unsigned long long mask = __ballot(keep);
        if (keep) {
            const int idx = __popcll(mask & ((1ULL << t) - 1ULL));
            lx_s[idx]  = lx;
            dy2_s[idx] = dy2;
            w_s[idx]   = invn[b * NN + t];
        }
        if (t == 0) cnt_s = (int)__popcll(mask);
    }
    __syncthreads();

    const int   cnt = cnt_s;
    const float xf  = (float)t;
    float acc = 0.0f;
    for (int j = 0; j < cnt; ++j) {
        const float dx = xf - lx_s[j];
        const float e  = __builtin_amdgcn_exp2f(c2 * (dx * dx + dy2_s[j]));
        acc = fmaf(e, w_s[j], acc);
    }
    out[(b * HH + y) * WW + t] = acc;
}

extern "C" void kernel_launch(void* const* d_in, const int* in_sizes, int n_in,
                              void* d_out, int out_size, void* d_ws, size_t ws_size,
                              hipStream_t stream) {
    // d_in[0]: batch_images (B,3,H,W) f32 — only shapes matter, unused.
    // d_in[1]: batch_labels (B,N,2) f32
    // d_in[2]: sigma scalar f32
    const float* labels = (const float*)d_in[1];
    const float* sigma  = (const float*)d_in[2];
    float*       out    = (float*)d_out;
    float*       invn   = (float*)d_ws;       // B*N floats = 1 KB

    norm_kernel<<<BB * NN, 64, 0, stream>>>(labels, sigma, invn);
    density_kernel<<<BB * HH, 512, 0, stream>>>(labels, sigma, invn, out);
}

// Round 2
// 9.692 us; speedup vs baseline: 1.3832x; 1.3832x over previous
//
#include <hip/hip_runtime.h>

// Problem constants: B=4, N=64 labels, H=W=512.
#define BB 4
#define NN 64
#define HH 512
#define WW 512
#define RPB 8                      // rows per block -> grid = 4*64 = 256 = #CUs
#define LOG2E 1.4426950408889634f
#define CUT 18.0f                  // drop label if exp2(c2*dy2) < 2^-18 for all rows

// One fused kernel. Block = (b, 8 rows). 512 threads = one x-column each.
// Phase 1: wave 0 ballot-compacts labels whose gaussian reaches these rows.
// Phase 2: wave j computes survivor j's normalization 1/(Sx*Sy) (full-grid
//          sums, 8 points/lane + 64-lane butterfly).
// Phase 3: tiny LDS table eyw[j][r] = exp2(c2*dy^2)*w for the 8 rows.
// Phase 4: per thread: ex = exp2(c2*dx^2); acc[r] += ex*eyw[j][r]; 8 stores.
__global__ __launch_bounds__(512) void fused_density_kernel(
    const float* __restrict__ labels,   // (B,N,2)
    const float* __restrict__ sigma,    // scalar
    float* __restrict__ out)            // (B,1,H,W)
{
    const int b    = blockIdx.x / (HH / RPB);          // 0..3
    const int y0   = (blockIdx.x % (HH / RPB)) * RPB;  // first row of block
    const int t    = threadIdx.x;                      // 0..511 = x
    const int wave = t >> 6;
    const int lane = t & 63;

    __shared__ float lx_s[NN];
    __shared__ float ly_s[NN];
    __shared__ float w_s[NN];
    __shared__ float eyw_s[NN][RPB];
    __shared__ int   cnt_s;

    const float s    = sigma[0];
    const float c2   = -LOG2E / (2.0f * s * s);  // exp(-d2/(2s^2)) = exp2(c2*d2)
    const float rad  = __builtin_sqrtf(CUT / (-c2));

    // ---- Phase 1: compact surviving labels (wave 0 only, NN==64) ----
    if (wave == 0) {
        const float lx = labels[(b * NN + lane) * 2 + 0];
        const float ly = labels[(b * NN + lane) * 2 + 1];
        // distance from ly to nearest row in [y0, y0+RPB-1]
        const float dlo  = (float)y0 - ly;
        const float dhi  = ly - (float)(y0 + RPB - 1);
        const float dmin = fmaxf(fmaxf(dlo, dhi), 0.0f);
        const bool keep  = dmin < rad;
        const unsigned long long mask = __ballot(keep);
        if (keep) {
            const int idx = __popcll(mask & ((1ULL << lane) - 1ULL));
            lx_s[idx] = lx;
            ly_s[idx] = ly;
        }
        if (lane == 0) cnt_s = (int)__popcll(mask);
    }
    __syncthreads();
    const int cnt = cnt_s;

    // ---- Phase 2: normalization per survivor, one wave each ----
    for (int j = wave; j < cnt; j += 8) {
        const float lx = lx_s[j], ly = ly_s[j];
        float sx = 0.0f, sy = 0.0f;
#pragma unroll
        for (int k = 0; k < WW; k += 64) {
            const float v  = (float)(lane + k);
            const float dx = v - lx;
            const float dy = v - ly;
            sx += __builtin_amdgcn_exp2f(c2 * dx * dx);
            sy += __builtin_amdgcn_exp2f(c2 * dy * dy);
        }
#pragma unroll
        for (int off = 32; off > 0; off >>= 1) {
            sx += __shfl_xor(sx, off, 64);
            sy += __shfl_xor(sy, off, 64);
        }
        if (lane == 0) w_s[j] = 1.0f / (sx * sy);
    }
    __syncthreads();

    // ---- Phase 3: y-factor * weight table ----
    if (t < cnt * RPB) {
        const int j = t >> 3, r = t & (RPB - 1);
        const float dy = (float)(y0 + r) - ly_s[j];
        eyw_s[j][r] = __builtin_amdgcn_exp2f(c2 * dy * dy) * w_s[j];
    }
    __syncthreads();

    // ---- Phase 4: accumulate 8 rows, one column per thread ----
    float acc[RPB];
#pragma unroll
    for (int r = 0; r < RPB; ++r) acc[r] = 0.0f;
    const float xf = (float)t;
    for (int j = 0; j < cnt; ++j) {
        const float dx = xf - lx_s[j];
        const float ex = __builtin_amdgcn_exp2f(c2 * dx * dx);
#pragma unroll
        for (int r = 0; r < RPB; ++r)
            acc[r] = fmaf(ex, eyw_s[j][r], acc[r]);
    }
#pragma unroll
    for (int r = 0; r < RPB; ++r)
        out[(b * HH + y0 + r) * WW + t] = acc[r];
}

extern "C" void kernel_launch(void* const* d_in, const int* in_sizes, int n_in,
                              void* d_out, int out_size, void* d_ws, size_t ws_size,
                              hipStream_t stream) {
    // d_in[0]: batch_images (unused), d_in[1]: batch_labels (B,N,2), d_in[2]: sigma
    const float* labels = (const float*)d_in[1];
    const float* sigma  = (const float*)d_in[2];
    float*       out    = (float*)d_out;

    fused_density_kernel<<<BB * (HH / RPB), 512, 0, stream>>>(labels, sigma, out);
}